// Round 1
// 424.834 us; speedup vs baseline: 1.0090x; 1.0090x over previous
//
#include <hip/hip_runtime.h>

#define FIN 128
#define H1_ 50
#define H2_ 10
#define H2P 12                 // padded z row stride (48B, 16B-aligned rows)

#define BKT_SHIFT 7
#define BKT_W 128              // nodes per fine bucket
#define NB_MAX 800             // >= ceil(100000/128) = 782
#define SB_SHIFT 11
#define SB_W 2048              // nodes per super-bucket (= 16 fine buckets)
#define NSB_MAX 64             // >= ceil(100000/2048) = 49
#define SB_CAP 81920           // fixed segment capacity (1.25x expected 65536)
#define P1_CHUNK 8192          // edges per block, SB partition
#define P1F_CHUNK 4096         // edges per block, fine partition

// ---------------- bf16 helpers (RNE) ----------------

__device__ inline float bf2f(unsigned int u16) {
    union { unsigned int i; float f; } c; c.i = u16 << 16; return c.f;
}
__device__ inline unsigned short f2bf(float f) {
    union { float f; unsigned int i; } c; c.f = f;
    unsigned int x = c.i;
    return (unsigned short)((x + 0x7FFFu + ((x >> 16) & 1u)) >> 16);
}

// ======== level 1 (fused): SB partition + fine histogram in one pass ========
// record: src (bits 0..16) | dst-within-SB (bits 17..27)
// SB segments are fixed-capacity: base = sb*SB_CAP (no scan dependency).

__global__ __launch_bounds__(256) void partition_sb(const int* __restrict__ src,
                                                    const int* __restrict__ dst,
                                                    int* __restrict__ sbcnt,
                                                    int* __restrict__ bcnt,
                                                    int* __restrict__ pairbuf1,
                                                    int E, int nsb) {
    __shared__ int lh[NB_MAX];     // fine histogram
    __shared__ int lhs[NSB_MAX];   // SB local cursor
    __shared__ int lbs[NSB_MAX];   // SB reserved global base
    int tid = threadIdx.x;
    for (int i = tid; i < NB_MAX; i += 256) lh[i] = 0;
    if (tid < NSB_MAX) lhs[tid] = 0;
    __syncthreads();
    int lo = blockIdx.x * P1_CHUNK;
    int hi = min(lo + P1_CHUNK, E);
    for (int e = lo + tid; e < hi; e += 256)
        atomicAdd(&lh[dst[e] >> BKT_SHIFT], 1);
    __syncthreads();
    if (tid < nsb) {
        int c = 0;
#pragma unroll
        for (int j = 0; j < 16; ++j) {
            int idx = tid * 16 + j;
            c += (idx < NB_MAX) ? lh[idx] : 0;
        }
        lbs[tid] = c ? (tid * SB_CAP + atomicAdd(&sbcnt[tid], c)) : 0;
    }
    for (int i = tid; i < NB_MAX; i += 256) {
        int c = lh[i];
        if (c) atomicAdd(&bcnt[i], c);
    }
    __syncthreads();
    for (int e = lo + tid; e < hi; e += 256) {
        int sv = src[e], d = dst[e];
        int b = d >> SB_SHIFT;
        int r = atomicAdd(&lhs[b], 1);
        pairbuf1[lbs[b] + r] = sv | ((d & (SB_W - 1)) << 17);
    }
}

// single block: scan fine counts -> bbase/bcursor
__global__ __launch_bounds__(256) void bucket_scan(const int* __restrict__ bcnt,
                                                   int* __restrict__ bbase,
                                                   int* __restrict__ bcursor,
                                                   int nb2, int E) {
    __shared__ int s[256];
    int t = threadIdx.x;
    int base = t * 4;
    int v0 = (base + 0 < nb2) ? bcnt[base + 0] : 0;
    int v1 = (base + 1 < nb2) ? bcnt[base + 1] : 0;
    int v2 = (base + 2 < nb2) ? bcnt[base + 2] : 0;
    int v3 = (base + 3 < nb2) ? bcnt[base + 3] : 0;
    int tsum = v0 + v1 + v2 + v3;
    s[t] = tsum;
    __syncthreads();
    for (int off = 1; off < 256; off <<= 1) {
        int x = (t >= off) ? s[t - off] : 0;
        __syncthreads();
        s[t] += x;
        __syncthreads();
    }
    int excl = s[t] - tsum;
    if (t == 0) bbase[nb2] = E;
    if (base + 0 < nb2) { bbase[base + 0] = excl; bcursor[base + 0] = excl; }
    excl += v0;
    if (base + 1 < nb2) { bbase[base + 1] = excl; bcursor[base + 1] = excl; }
    excl += v1;
    if (base + 2 < nb2) { bbase[base + 2] = excl; bcursor[base + 2] = excl; }
    excl += v2;
    if (base + 3 < nb2) { bbase[base + 3] = excl; bcursor[base + 3] = excl; }
}

// ======== level 2: partition each SB segment into its 16 fine buckets ======

__global__ __launch_bounds__(256) void partition_fine(const int* __restrict__ pairbuf1,
                                                      const int* __restrict__ sbcnt,
                                                      int* __restrict__ bcursor,
                                                      int* __restrict__ pairbuf2) {
    int sb = blockIdx.y;
    int cnt = sbcnt[sb];
    int rel = blockIdx.x * P1F_CHUNK;
    if (rel >= cnt) return;
    int lo = sb * SB_CAP + rel;
    int hi = sb * SB_CAP + min(rel + P1F_CHUNK, cnt);
    __shared__ int lh[16];
    __shared__ int lb[16];
    int tid = threadIdx.x;
    if (tid < 16) lh[tid] = 0;
    __syncthreads();
    for (int j = lo + tid; j < hi; j += 256)
        atomicAdd(&lh[(pairbuf1[j] >> 17) >> BKT_SHIFT], 1);
    __syncthreads();
    if (tid < 16) {
        int c = lh[tid];
        lb[tid] = c ? atomicAdd(&bcursor[sb * 16 + tid], c) : 0;
        lh[tid] = 0;
    }
    __syncthreads();
    for (int j = lo + tid; j < hi; j += 256) {
        int p = pairbuf1[j];
        int din = p >> 17;
        int fb = din >> BKT_SHIFT;
        int r = atomicAdd(&lh[fb], 1);
        pairbuf2[lb[fb] + r] = (p & 0x1FFFF) | ((din & (BKT_W - 1)) << 17);
    }
}

// ========== pass 2: per-bucket count + scan + rowptr/dinv + fill (fused) ==========

__global__ __launch_bounds__(256) void bucket_fill_scan(const int* __restrict__ pairbuf,
                                                        const int* __restrict__ bbase,
                                                        int* __restrict__ rowptr,
                                                        float* __restrict__ dinv,
                                                        int* __restrict__ ecol,
                                                        int N, int E) {
    __shared__ int cnt[BKT_W];
    __shared__ int sc[BKT_W];
    __shared__ int cur[BKT_W];
    int b = blockIdx.x;
    int base_node = b << BKT_SHIFT;
    int nnodes = min(BKT_W, N - base_node);
    int tid = threadIdx.x;
    if (tid < BKT_W) cnt[tid] = 0;
    __syncthreads();
    int lo = bbase[b], hi = bbase[b + 1];
    for (int j = lo + tid; j < hi; j += 256)
        atomicAdd(&cnt[pairbuf[j] >> 17], 1);
    __syncthreads();
    int c = (tid < BKT_W) ? cnt[tid] : 0;
    if (tid < BKT_W) sc[tid] = c;
    __syncthreads();
    for (int off = 1; off < BKT_W; off <<= 1) {
        int xv = (tid >= off && tid < BKT_W) ? sc[tid - off] : 0;
        __syncthreads();
        if (tid < BKT_W) sc[tid] += xv;
        __syncthreads();
    }
    if (tid < nnodes) {
        int rp = lo + sc[tid] - c;           // exclusive prefix within bucket
        rowptr[base_node + tid] = rp;
        cur[tid] = rp;
        dinv[base_node + tid] = rsqrtf(1.0f + (float)c);   // deg incl self-loop
    }
    __syncthreads();
    for (int j = lo + tid; j < hi; j += 256) {
        int p = pairbuf[j];
        int pos = atomicAdd(&cur[p >> 17], 1);
        ecol[pos] = p & 0x1FFFF;
    }
    if (b == (int)gridDim.x - 1 && tid == 0) rowptr[N] = E;
}

// ======== GEMM1 v4: 4-node x 8-feat thread tile, W k-sliced ========
// 128 nodes/block, 256 threads: quad q=tid>>3 -> nodes 4q..4q+3, g=tid&7 -> feats 8g..
// Per k-step: 4x ds_read_b32 (x) + 2x ds_read_b128 (W) for 32 FMAs (1.5 B/FMA).

#define G1_NODES 128
#define SX_PITCH 132
#define KCHUNK 32
__global__ __launch_bounds__(256) void gemm1_kernel(const float* __restrict__ x,
                                                    const float* __restrict__ W1,
                                                    const float* __restrict__ dinv,
                                                    unsigned short* __restrict__ st1p, int N) {
    __shared__ float sX[G1_NODES * SX_PITCH]; // 67.6 KB
    __shared__ float sW[KCHUNK * 64];         // 8 KB per k-chunk
    int tid = threadIdx.x;
    int nb = blockIdx.x * G1_NODES;
    {
        const float4* x4 = (const float4*)(x + (size_t)nb * FIN);
        for (int i = tid; i < G1_NODES * 32; i += 256) {   // 4096 float4 stages
            int ln = i >> 5, kk = i & 31;
            float4 v = (nb + ln < N) ? x4[(size_t)ln * 32 + kk]
                                     : make_float4(0.f, 0.f, 0.f, 0.f);
            *(float4*)(&sX[ln * SX_PITCH + kk * 4]) = v;
        }
    }
    int q = tid >> 3;         // 0..31
    int g = tid & 7;          // 0..7
    const float* xr0 = &sX[(4 * q + 0) * SX_PITCH];
    const float* xr1 = &sX[(4 * q + 1) * SX_PITCH];
    const float* xr2 = &sX[(4 * q + 2) * SX_PITCH];
    const float* xr3 = &sX[(4 * q + 3) * SX_PITCH];
    float acc[4][8];
#pragma unroll
    for (int i = 0; i < 4; ++i)
#pragma unroll
        for (int j = 0; j < 8; ++j) acc[i][j] = 0.0f;

    for (int kc = 0; kc < FIN / KCHUNK; ++kc) {
        __syncthreads();     // protect sW from previous iteration's readers
        for (int i = tid; i < KCHUNK * 64; i += 256) {
            int k = i >> 6, f = i & 63;
            sW[i] = (f < H1_) ? W1[(kc * KCHUNK + k) * H1_ + f] : 0.0f;
        }
        __syncthreads();
        int kb = kc * KCHUNK;
#pragma unroll 4
        for (int k = 0; k < KCHUNK; ++k) {
            float xv0 = xr0[kb + k];
            float xv1 = xr1[kb + k];
            float xv2 = xr2[kb + k];
            float xv3 = xr3[kb + k];
            const float* w = &sW[k * 64 + g * 8];
#pragma unroll
            for (int j = 0; j < 8; ++j) {
                float wv = w[j];
                acc[0][j] = fmaf(xv0, wv, acc[0][j]);
                acc[1][j] = fmaf(xv1, wv, acc[1][j]);
                acc[2][j] = fmaf(xv2, wv, acc[2][j]);
                acc[3][j] = fmaf(xv3, wv, acc[3][j]);
            }
        }
    }
#pragma unroll
    for (int i = 0; i < 4; ++i) {
        int node = nb + 4 * q + i;
        if (node >= N) continue;
        float di = dinv[node];
        unsigned short o[8];
#pragma unroll
        for (int j = 0; j < 8; ++j) o[j] = f2bf(acc[i][j] * di);
        uint4 pk;
        pk.x = (unsigned)o[0] | ((unsigned)o[1] << 16);
        pk.y = (unsigned)o[2] | ((unsigned)o[3] << 16);
        pk.z = (unsigned)o[4] | ((unsigned)o[5] << 16);
        pk.w = (unsigned)o[6] | ((unsigned)o[7] << 16);
        *(uint4*)(st1p + (size_t)node * 64 + g * 8) = pk;
    }
}

// ============ aggregate layer 1: bf16 gather, fp32 accumulate ============

#define F2 25
__global__ __launch_bounds__(256) void csr_aggregate1(const unsigned short* __restrict__ st,
                                                      const int* __restrict__ rowptr,
                                                      const int* __restrict__ ecol,
                                                      const float* __restrict__ dinv,
                                                      const float* __restrict__ b,
                                                      float* __restrict__ out, int N) {
    int idx = blockIdx.x * blockDim.x + threadIdx.x;
    if (idx >= N * F2) return;
    int d  = idx / F2;
    int fp = idx - d * F2;
    int fo = 2 * fp;
    unsigned int self2 = *(const unsigned int*)(st + (size_t)d * 64 + fo);
    float acc0 = bf2f(self2 & 0xFFFFu);
    float acc1 = bf2f(self2 >> 16);
    int j = rowptr[d], end = rowptr[d + 1];
    for (; j + 3 < end; j += 4) {
        int s0 = ecol[j], s1 = ecol[j + 1], s2 = ecol[j + 2], s3 = ecol[j + 3];
        unsigned int v0 = *(const unsigned int*)(st + (size_t)s0 * 64 + fo);
        unsigned int v1 = *(const unsigned int*)(st + (size_t)s1 * 64 + fo);
        unsigned int v2 = *(const unsigned int*)(st + (size_t)s2 * 64 + fo);
        unsigned int v3 = *(const unsigned int*)(st + (size_t)s3 * 64 + fo);
        acc0 += (bf2f(v0 & 0xFFFFu) + bf2f(v1 & 0xFFFFu)) + (bf2f(v2 & 0xFFFFu) + bf2f(v3 & 0xFFFFu));
        acc1 += (bf2f(v0 >> 16) + bf2f(v1 >> 16)) + (bf2f(v2 >> 16) + bf2f(v3 >> 16));
    }
    for (; j < end; ++j) {
        unsigned int v = *(const unsigned int*)(st + (size_t)ecol[j] * 64 + fo);
        acc0 += bf2f(v & 0xFFFFu);
        acc1 += bf2f(v >> 16);
    }
    float vd = dinv[d];
    float r0 = fmaxf(fmaf(vd, acc0, b[fo]),     0.0f);
    float r1 = fmaxf(fmaf(vd, acc1, b[fo + 1]), 0.0f);
    *(float2*)(out + (size_t)d * H1_ + fo) = make_float2(r0, r1);
}

// ================= GEMM2: st2[N,10] = (h @ W2) * dinv[node] =================

__global__ __launch_bounds__(256) void gemm2_kernel(const float* __restrict__ h,
                                                    const float* __restrict__ W2,
                                                    const float* __restrict__ dinv,
                                                    float* __restrict__ st2, int n) {
    __shared__ float sW[H1_ * H2_];   // 2 KB
    int tid = threadIdx.x;
    for (int i = tid; i < H1_ * H2_; i += 256) sW[i] = W2[i];
    __syncthreads();
    int idx = blockIdx.x * blockDim.x + tid;
    if (idx >= n) return;
    int node = idx / H2_;
    int f    = idx - node * H2_;
    const float* hr = &h[node * H1_];
    float acc = 0.0f;
#pragma unroll
    for (int k = 0; k < H1_; ++k) acc = fmaf(hr[k], sW[k * H2_ + f], acc);
    st2[idx] = acc * dinv[node];
}

// ============ aggregate layer 2 (fp32, F=10, padded output stride) ============
// Reads st (stride F), writes out (stride OS >= F). Padding floats never read
// by decode (it loads exactly floats 0..9 of each row).

template <int F, int OS, bool RELU>
__global__ __launch_bounds__(256) void csr_aggregate(const float* __restrict__ st,
                                                     const int* __restrict__ rowptr,
                                                     const int* __restrict__ ecol,
                                                     const float* __restrict__ dinv,
                                                     const float* __restrict__ b,
                                                     float* __restrict__ out, int N) {
    int idx = blockIdx.x * blockDim.x + threadIdx.x;
    if (idx >= N * F) return;
    int d = idx / F;
    int f = idx - d * F;
    float acc = st[idx];            // self-loop term
    int j = rowptr[d], end = rowptr[d + 1];
    for (; j + 3 < end; j += 4) {
        int s0 = ecol[j], s1 = ecol[j + 1], s2 = ecol[j + 2], s3 = ecol[j + 3];
        float a0 = st[s0 * F + f], a1 = st[s1 * F + f];
        float a2 = st[s2 * F + f], a3 = st[s3 * F + f];
        acc += (a0 + a1) + (a2 + a3);
    }
    for (; j < end; ++j) acc += st[ecol[j] * F + f];
    float v = fmaf(dinv[d], acc, b[f]);
    out[(size_t)d * OS + f] = RELU ? fmaxf(v, 0.0f) : v;
}

// ================= decode (padded z rows: float4+float4+float2 gathers) =======
// z rows are H2P=12 floats (48B), 16B-aligned -> 3 vmem requests per row
// instead of 5. Index loads and logits store are non-temporal so the 25.6MB
// index stream / 12.5MB store don't evict the 4.8MB z table from L2.

__global__ __launch_bounds__(256) void decode_kernel(const float* __restrict__ z,
                                                     const int* __restrict__ pos,
                                                     const int* __restrict__ neg,
                                                     float* __restrict__ logits, int EP) {
    int i = blockIdx.x * blockDim.x + threadIdx.x;
    if (i >= 2 * EP) return;
    int a, b;
    if (i < EP) {
        a = __builtin_nontemporal_load(&pos[i]);
        b = __builtin_nontemporal_load(&pos[EP + i]);
    } else {
        int j = i - EP;
        a = __builtin_nontemporal_load(&neg[j]);
        b = __builtin_nontemporal_load(&neg[EP + j]);
    }
    const float* za = z + (size_t)a * H2P;
    const float* zb = z + (size_t)b * H2P;
    float4 a0 = *(const float4*)(za);
    float4 a1 = *(const float4*)(za + 4);
    float2 a2 = *(const float2*)(za + 8);
    float4 b0 = *(const float4*)(zb);
    float4 b1 = *(const float4*)(zb + 4);
    float2 b2 = *(const float2*)(zb + 8);
    float acc = a0.x * b0.x;
    acc = fmaf(a0.y, b0.y, acc);
    acc = fmaf(a0.z, b0.z, acc);
    acc = fmaf(a0.w, b0.w, acc);
    acc = fmaf(a1.x, b1.x, acc);
    acc = fmaf(a1.y, b1.y, acc);
    acc = fmaf(a1.z, b1.z, acc);
    acc = fmaf(a1.w, b1.w, acc);
    acc = fmaf(a2.x, b2.x, acc);
    acc = fmaf(a2.y, b2.y, acc);
    __builtin_nontemporal_store(acc, &logits[i]);
}

// ================= launch =================

extern "C" void kernel_launch(void* const* d_in, const int* in_sizes, int n_in,
                              void* d_out, int out_size, void* d_ws, size_t ws_size,
                              hipStream_t stream) {
    const float* x   = (const float*)d_in[0];
    const float* W1  = (const float*)d_in[1];
    const float* b1  = (const float*)d_in[2];
    const float* W2  = (const float*)d_in[3];
    const float* b2  = (const float*)d_in[4];
    const int* train = (const int*)d_in[5];
    const int* pos   = (const int*)d_in[6];
    const int* neg   = (const int*)d_in[7];

    const int N  = in_sizes[0] / FIN;       // 100000
    const int E  = in_sizes[5] / 2;         // 3200000
    const int EP = in_sizes[6] / 2;         // 1600000

    const int* tsrc = train;
    const int* tdst = train + E;

    // ---- workspace layout (~37 MB peak) ----
    // ints: rowptr[N+1] | bcnt[NB_MAX] | sbcnt[NSB_MAX] | bbase[NB_MAX+1] | bcursor[NB_MAX]
    // floats: dinv[N]
    // regA = 32N floats (12.8MB): pairbuf2 int[E=32N] -> st1p bf16[N*64] -> st2[10N]|out2[12N]
    // regB = 50N floats (20MB):   pairbuf1 int[49*SB_CAP=16.1MB] -> out1[50N]
    size_t off = 0;
    int* rowptr   = (int*)d_ws;              off += (size_t)N + 1;
    int* bcnt     = (int*)d_ws + off;        off += NB_MAX;
    int* sbcnt    = (int*)d_ws + off;        off += NSB_MAX;
    int* bbase    = (int*)d_ws + off;        off += NB_MAX + 1;
    int* bcursor  = (int*)d_ws + off;        off += NB_MAX;
    float* dinv   = (float*)d_ws + off;      off += N;
    off = (off + 3) & ~(size_t)3;            // 16B-align
    float* regA   = (float*)d_ws + off;      off += (size_t)32 * N;
    float* regB   = (float*)d_ws + off;
    int* pairbuf2 = (int*)regA;                      // E ints, dead after fill
    unsigned short* st1p = (unsigned short*)regA;    // 64N ushorts = 128N bytes
    float* st2    = regA;                            // overlays st1p after agg1
    float* out2   = regA + (size_t)10 * N;           // z, padded stride 12 (12N floats)
    int* pairbuf1 = (int*)regB;                      // 49*SB_CAP ints, dead after fine
    float* out1   = regB;                            // h after relu, 50N floats
    int* ecol     = (int*)d_out;                     // E ints; dead before decode
    float* logits = (float*)d_out;

    const int NB2 = (N + BKT_W - 1) >> BKT_SHIFT;   // 782 <= NB_MAX
    const int NSB = (N + SB_W - 1) >> SB_SHIFT;     // 49 <= NSB_MAX
    const int P1B = (E + P1_CHUNK - 1) / P1_CHUNK;  // 391
    const int P1FB = (SB_CAP + P1F_CHUNK - 1) / P1F_CHUNK;   // 20

    // ---- CSR build (fused count+partition, fixed-capacity SB segments) ----
    hipMemsetAsync(bcnt, 0, (NB_MAX + NSB_MAX) * sizeof(int), stream);  // bcnt + sbcnt
    partition_sb<<<P1B, 256, 0, stream>>>(tsrc, tdst, sbcnt, bcnt, pairbuf1, E, NSB);
    bucket_scan<<<1, 256, 0, stream>>>(bcnt, bbase, bcursor, NB2, E);
    partition_fine<<<dim3(P1FB, NSB), 256, 0, stream>>>(pairbuf1, sbcnt, bcursor, pairbuf2);
    bucket_fill_scan<<<NB2, 256, 0, stream>>>(pairbuf2, bbase, rowptr, dinv, ecol, N, E);

    // ---- layer 1 ----
    gemm1_kernel<<<(N + G1_NODES - 1) / G1_NODES, 256, 0, stream>>>(x, W1, dinv, st1p, N);
    csr_aggregate1<<<(N * F2 + 255) / 256, 256, 0, stream>>>(
        st1p, rowptr, ecol, dinv, b1, out1, N);

    // ---- layer 2 ----
    gemm2_kernel<<<(N * H2_ + 255) / 256, 256, 0, stream>>>(out1, W2, dinv, st2, N * H2_);
    csr_aggregate<H2_, H2P, false><<<(N * H2_ + 255) / 256, 256, 0, stream>>>(
        st2, rowptr, ecol, dinv, b2, out2, N);

    // ---- decode ----
    decode_kernel<<<(2 * EP + 255) / 256, 256, 0, stream>>>(out2, pos, neg, logits, EP);
}